// Round 1
// baseline (652.028 us; speedup 1.0000x reference)
//
#include <hip/hip_runtime.h>
#include <hip/hip_bf16.h>

#define N_NODES 50000
#define D_FEAT  256
#define G_GROUPS 4
#define E_EDGES 800000
#define DG      64
#define M_SEG   (G_GROUPS * N_NODES)        // 200000 segments
#define TOT_E   (G_GROUPS * E_EDGES)        // 3200000 edges
#define M_PAD   50048                       // 391 * 128

// counting-sort scan geometry
#define SCAN_T      256
#define SCAN_ELEMS  1024                     // 4 per thread
#define SCAN_BLOCKS ((M_SEG + SCAN_ELEMS - 1) / SCAN_ELEMS)   // 196

typedef short bf16x8 __attribute__((ext_vector_type(8)));   // 8 bf16 (4 VGPRs)
typedef float f32x4  __attribute__((ext_vector_type(4)));

__device__ __forceinline__ unsigned short f2bf(float f) {
    unsigned int u = __float_as_uint(f);
    u += 0x7FFF + ((u >> 16) & 1);          // RNE
    return (unsigned short)(u >> 16);
}
__device__ __forceinline__ float bf2f(unsigned short h) {
    return __uint_as_float((unsigned int)h << 16);
}

// ---------------------------------------------------------------------------
// x (f32 [N,256]) -> x_bf (bf16). 8 elems / thread.
// ---------------------------------------------------------------------------
__global__ __launch_bounds__(256) void convert_x_kernel(
    const float* __restrict__ x, unsigned short* __restrict__ xb)
{
    const long long base = ((long long)blockIdx.x * 256 + threadIdx.x) * 8;
    if (base >= (long long)N_NODES * D_FEAT) return;
    const float4 v0 = *(const float4*)&x[base];
    const float4 v1 = *(const float4*)&x[base + 4];
    unsigned short r[8];
    r[0] = f2bf(v0.x); r[1] = f2bf(v0.y); r[2] = f2bf(v0.z); r[3] = f2bf(v0.w);
    r[4] = f2bf(v1.x); r[5] = f2bf(v1.y); r[6] = f2bf(v1.z); r[7] = f2bf(v1.w);
    *(uint4*)&xb[base] = *(const uint4*)r;
}

// W [K=256, N=256] f32 -> Wt [n][k] bf16 (transposed, k-contiguous)
__global__ __launch_bounds__(256) void convert_w_kernel(
    const float* __restrict__ W, unsigned short* __restrict__ Wt)
{
    const int n = blockIdx.x;       // 256 blocks
    const int k = threadIdx.x;      // 256 threads
    Wt[n * D_FEAT + k] = f2bf(W[k * D_FEAT + n]);
}

// ---------------------------------------------------------------------------
// Counting sort, pass 1: per-segment edge counts.
// ---------------------------------------------------------------------------
__global__ __launch_bounds__(256) void count_kernel(
    const int* __restrict__ edge_row, int* __restrict__ cnt)
{
    const int i = blockIdx.x * 256 + threadIdx.x;
    if (i >= TOT_E) return;
    const int g = i / E_EDGES;
    atomicAdd(&cnt[g * N_NODES + edge_row[i]], 1);
}

// pass 2a: per-block partial sums of cnt (1024 elems / block)
__global__ __launch_bounds__(SCAN_T) void scan_partial_kernel(
    const int* __restrict__ cnt, int* __restrict__ partial)
{
    __shared__ int sh[SCAN_T];
    const int t = threadIdx.x;
    const int base = blockIdx.x * SCAN_ELEMS + t * 4;   // M_SEG % 4 == 0
    int4 v = make_int4(0, 0, 0, 0);
    if (base < M_SEG) v = *(const int4*)&cnt[base];
    sh[t] = v.x + v.y + v.z + v.w;
    __syncthreads();
    #pragma unroll
    for (int off = 128; off > 0; off >>= 1) {
        if (t < off) sh[t] += sh[t + off];
        __syncthreads();
    }
    if (t == 0) partial[blockIdx.x] = sh[0];
}

// pass 2b: single-block exclusive scan of the 196 partials (in place)
__global__ __launch_bounds__(SCAN_T) void scan_top_kernel(
    int* __restrict__ partial, int* __restrict__ ofs)
{
    __shared__ int sh[SCAN_T];
    const int t = threadIdx.x;
    const int v = (t < SCAN_BLOCKS) ? partial[t] : 0;
    sh[t] = v;
    __syncthreads();
    #pragma unroll
    for (int off = 1; off < SCAN_T; off <<= 1) {
        const int add = (t >= off) ? sh[t - off] : 0;
        __syncthreads();
        sh[t] += add;
        __syncthreads();
    }
    if (t < SCAN_BLOCKS) partial[t] = sh[t] - v;   // exclusive
    if (t == 0) ofs[M_SEG] = TOT_E;
}

// pass 2c: final exclusive scan; writes ofs[] (CSR starts for spmm) and
// rewrites cnt[] with the same starts (scatter cursors).
__global__ __launch_bounds__(SCAN_T) void scan_final_kernel(
    int* __restrict__ cnt, const int* __restrict__ partial, int* __restrict__ ofs)
{
    __shared__ int sh[SCAN_T];
    const int t = threadIdx.x;
    const int base = blockIdx.x * SCAN_ELEMS + t * 4;
    int4 v = make_int4(0, 0, 0, 0);
    if (base < M_SEG) v = *(const int4*)&cnt[base];
    const int tsum = v.x + v.y + v.z + v.w;
    sh[t] = tsum;
    __syncthreads();
    #pragma unroll
    for (int off = 1; off < SCAN_T; off <<= 1) {
        const int add = (t >= off) ? sh[t - off] : 0;
        __syncthreads();
        sh[t] += add;
        __syncthreads();
    }
    if (base < M_SEG) {
        int o = partial[blockIdx.x] + sh[t] - tsum;
        int4 w;
        w.x = o;
        w.y = o + v.x;
        w.z = w.y + v.y;
        w.w = w.z + v.z;
        *(int4*)&ofs[base] = w;
        *(int4*)&cnt[base] = w;   // scatter cursors start at segment offset
    }
}

// pass 3: scatter packed {col, val_bits} into CSR order.
__global__ __launch_bounds__(256) void scatter_kernel(
    const int* __restrict__ edge_row, const int* __restrict__ edge_col,
    const float* __restrict__ edge_val, int* __restrict__ cur,
    int2* __restrict__ ep)
{
    const int i = blockIdx.x * 256 + threadIdx.x;
    if (i >= TOT_E) return;
    const int g = i / E_EDGES;
    const int seg = g * N_NODES + edge_row[i];
    const int pos = atomicAdd(&cur[seg], 1);
    ep[pos] = make_int2(edge_col[i], __float_as_int(edge_val[i]));
}

// ---------------------------------------------------------------------------
// CSR gather SpMM: one wave per (g,row); contiguous edge run, no pointer
// chase. Unroll-4 gathers in flight; bf16 gathers, f32 acc, bf16 store.
// ---------------------------------------------------------------------------
__global__ __launch_bounds__(256) void spmm_csr_kernel(
    const unsigned short* __restrict__ xb, const int2* __restrict__ ep,
    const int* __restrict__ ofs, unsigned short* __restrict__ tmpb)
{
    const int w = (blockIdx.x * 256 + threadIdx.x) >> 6;   // segment, exact
    const int lane = threadIdx.x & 63;
    const int g = w / N_NODES;
    const int row = w - g * N_NODES;

    const unsigned short* __restrict__ xcol = xb + g * DG + lane;

    const int s = ofs[w];
    const int e = ofs[w + 1];

    float acc = 0.f;
    int j = s;
    for (; j + 4 <= e; j += 4) {
        const int2 p0 = ep[j + 0];
        const int2 p1 = ep[j + 1];
        const int2 p2 = ep[j + 2];
        const int2 p3 = ep[j + 3];
        acc += __int_as_float(p0.y) * bf2f(xcol[p0.x * D_FEAT]);
        acc += __int_as_float(p1.y) * bf2f(xcol[p1.x * D_FEAT]);
        acc += __int_as_float(p2.y) * bf2f(xcol[p2.x * D_FEAT]);
        acc += __int_as_float(p3.y) * bf2f(xcol[p3.x * D_FEAT]);
    }
    for (; j < e; ++j) {
        const int2 p = ep[j];
        acc += __int_as_float(p.y) * bf2f(xcol[p.x * D_FEAT]);
    }
    tmpb[(long long)row * D_FEAT + g * DG + lane] = f2bf(acc);
}

// ---------------------------------------------------------------------------
// MFMA GEMM: C[M,256] = tmp_bf @ W + bias.  A: [M_PAD,256] bf16 row-major,
// Bt: [256,256] bf16 n-major/k-contiguous. 128x128 tile, BK=32, 4 waves.
// ---------------------------------------------------------------------------
#define TBK 32
#define LDP 40   // padded LDS row (ushorts): 80B stride spreads all 32 banks

__global__ __launch_bounds__(256) void gemm_mfma_kernel(
    const unsigned short* __restrict__ A, const unsigned short* __restrict__ Bt,
    const float* __restrict__ bias, float* __restrict__ C)
{
    __shared__ unsigned short As[128][LDP];   // 10 KB
    __shared__ unsigned short Bs[128][LDP];   // 10 KB

    const int tid = threadIdx.x;
    const int wid = tid >> 6, lane = tid & 63;
    const int wm = (wid & 1) * 64, wn = (wid >> 1) * 64;
    const int lm = lane & 15, lq = lane >> 4;
    const int row0 = blockIdx.x * 128, col0 = blockIdx.y * 128;

    f32x4 acc[4][4] = {};

    for (int k0 = 0; k0 < D_FEAT; k0 += TBK) {
        // A tile: 128 rows x 32 k; 64B/row = 4 x 16B chunks; 2 chunks/thread
        #pragma unroll
        for (int l = 0; l < 2; ++l) {
            const int chunk = tid + l * 256;     // 0..511
            const int r = chunk >> 2;
            const int c = (chunk & 3) * 8;
            uint4 v = make_uint4(0u, 0u, 0u, 0u);
            const int gr = row0 + r;
            if (gr < N_NODES)
                v = *(const uint4*)&A[(long long)gr * D_FEAT + k0 + c];
            *(uint4*)&As[r][c] = v;
        }
        #pragma unroll
        for (int l = 0; l < 2; ++l) {
            const int chunk = tid + l * 256;
            const int r = chunk >> 2;
            const int c = (chunk & 3) * 8;
            *(uint4*)&Bs[r][c] =
                *(const uint4*)&Bt[(long long)(col0 + r) * D_FEAT + k0 + c];
        }
        __syncthreads();

        bf16x8 af[4], bfr[4];
        #pragma unroll
        for (int mi = 0; mi < 4; ++mi)
            af[mi] = *(const bf16x8*)&As[wm + mi * 16 + lm][lq * 8];
        #pragma unroll
        for (int ni = 0; ni < 4; ++ni)
            bfr[ni] = *(const bf16x8*)&Bs[wn + ni * 16 + lm][lq * 8];
        #pragma unroll
        for (int mi = 0; mi < 4; ++mi)
            #pragma unroll
            for (int ni = 0; ni < 4; ++ni)
                acc[mi][ni] = __builtin_amdgcn_mfma_f32_16x16x32_bf16(
                    af[mi], bfr[ni], acc[mi][ni], 0, 0, 0);
        __syncthreads();
    }

    // D layout: col = lane&15, row = (lane>>4)*4 + reg
    #pragma unroll
    for (int mi = 0; mi < 4; ++mi) {
        #pragma unroll
        for (int ni = 0; ni < 4; ++ni) {
            const int n = col0 + wn + ni * 16 + lm;
            const float b = bias[n];
            #pragma unroll
            for (int r = 0; r < 4; ++r) {
                const int m = row0 + wm + mi * 16 + lq * 4 + r;
                if (m < N_NODES)
                    C[(long long)m * D_FEAT + n] = acc[mi][ni][r] + b;
            }
        }
    }
}

// ---------------------------------------------------------------------------
// Fallback path (atomic f32 spmm + f32 GEMM) — only if ws too small.
// ---------------------------------------------------------------------------
__global__ __launch_bounds__(256) void spmm_scatter_kernel(
    const float* __restrict__ x, const int* __restrict__ edge_row,
    const int* __restrict__ edge_col, const float* __restrict__ edge_val,
    float* __restrict__ tmp)
{
    const long long gtid = (long long)blockIdx.x * blockDim.x + threadIdx.x;
    const int wave = (int)(gtid >> 6);
    const int lane = threadIdx.x & 63;
    if (wave >= TOT_E) return;
    const int g = wave / E_EDGES;
    const int row = edge_row[wave];
    const int col = edge_col[wave];
    const float val = edge_val[wave];
    atomicAdd(&tmp[(long long)row * D_FEAT + g * DG + lane],
              val * x[(long long)col * D_FEAT + g * DG + lane]);
}

__global__ __launch_bounds__(256) void gemm_bias_kernel(
    const float* __restrict__ A, const float* __restrict__ W,
    const float* __restrict__ bias, float* __restrict__ C)
{
    __shared__ float Asf[64][68];
    __shared__ float Wsf[64][68];
    const int tid = threadIdx.x;
    const int tx = tid & 15, ty = tid >> 4;
    const int row0 = blockIdx.x * 64, col0 = blockIdx.y * 64;
    float acc[4][4] = {};
    for (int k0 = 0; k0 < D_FEAT; k0 += 64) {
        #pragma unroll
        for (int l = 0; l < 4; ++l) {
            const int linear = tid + l * 256;
            const int ar = linear >> 4, ac = (linear & 15) << 2;
            float4 v = make_float4(0.f, 0.f, 0.f, 0.f);
            const int gr = row0 + ar;
            if (gr < N_NODES) v = *(const float4*)&A[(long long)gr * D_FEAT + k0 + ac];
            Asf[ac + 0][ar] = v.x; Asf[ac + 1][ar] = v.y;
            Asf[ac + 2][ar] = v.z; Asf[ac + 3][ar] = v.w;
        }
        #pragma unroll
        for (int l = 0; l < 4; ++l) {
            const int linear = tid + l * 256;
            const int wr = linear >> 4, wc = (linear & 15) << 2;
            *(float4*)&Wsf[wr][wc] =
                *(const float4*)&W[(long long)(k0 + wr) * D_FEAT + col0 + wc];
        }
        __syncthreads();
        #pragma unroll
        for (int k = 0; k < 64; ++k) {
            const float4 a4 = *(const float4*)&Asf[k][ty * 4];
            const float4 b4 = *(const float4*)&Wsf[k][tx * 4];
            const float a[4] = {a4.x, a4.y, a4.z, a4.w};
            const float b[4] = {b4.x, b4.y, b4.z, b4.w};
            #pragma unroll
            for (int i = 0; i < 4; ++i)
                #pragma unroll
                for (int j = 0; j < 4; ++j) acc[i][j] += a[i] * b[j];
        }
        __syncthreads();
    }
    const float4 b4 = *(const float4*)&bias[col0 + tx * 4];
    #pragma unroll
    for (int i = 0; i < 4; ++i) {
        const int gr = row0 + ty * 4 + i;
        if (gr >= N_NODES) continue;
        float4 v;
        v.x = acc[i][0] + b4.x; v.y = acc[i][1] + b4.y;
        v.z = acc[i][2] + b4.z; v.w = acc[i][3] + b4.w;
        *(float4*)&C[(long long)gr * D_FEAT + col0 + tx * 4] = v;
    }
}

// ---------------------------------------------------------------------------
extern "C" void kernel_launch(void* const* d_in, const int* in_sizes, int n_in,
                              void* d_out, int out_size, void* d_ws, size_t ws_size,
                              hipStream_t stream)
{
    const float* x        = (const float*)d_in[0];
    const int*   edge_row = (const int*)d_in[1];
    const int*   edge_col = (const int*)d_in[2];
    const float* edge_val = (const float*)d_in[3];
    const float* weight   = (const float*)d_in[4];
    const float* bias     = (const float*)d_in[5];
    float* out = (float*)d_out;

    char* p = (char*)d_ws;
    auto alloc = [&](size_t bytes) {
        char* r = p;
        p += (bytes + 255) & ~(size_t)255;
        return r;
    };
    unsigned short* xb   = (unsigned short*)alloc((size_t)N_NODES * D_FEAT * 2); // 25.6 MB
    unsigned short* tmpb = (unsigned short*)alloc((size_t)M_PAD * D_FEAT * 2);   // 25.6 MB
    unsigned short* Wt   = (unsigned short*)alloc((size_t)D_FEAT * D_FEAT * 2);  // 128 KB
    int2* ep   = (int2*)alloc((size_t)TOT_E * sizeof(int2));                     // 25.6 MB
    int* cnt   = (int*)alloc((size_t)M_SEG * sizeof(int));                       // 800 KB
    int* ofs   = (int*)alloc((size_t)(M_SEG + 1) * sizeof(int));                 // 800 KB
    int* partial = (int*)alloc((size_t)SCAN_BLOCKS * sizeof(int));               // < 1 KB
    const size_t needed = (size_t)(p - (char*)d_ws);

    if (ws_size >= needed) {
        hipMemsetAsync(cnt, 0, (size_t)M_SEG * sizeof(int), stream);
        convert_x_kernel<<<(N_NODES * D_FEAT / 8 + 255) / 256, 256, 0, stream>>>(x, xb);
        convert_w_kernel<<<D_FEAT, D_FEAT, 0, stream>>>(weight, Wt);
        count_kernel<<<(TOT_E + 255) / 256, 256, 0, stream>>>(edge_row, cnt);
        scan_partial_kernel<<<SCAN_BLOCKS, SCAN_T, 0, stream>>>(cnt, partial);
        scan_top_kernel<<<1, SCAN_T, 0, stream>>>(partial, ofs);
        scan_final_kernel<<<SCAN_BLOCKS, SCAN_T, 0, stream>>>(cnt, partial, ofs);
        scatter_kernel<<<(TOT_E + 255) / 256, 256, 0, stream>>>(
            edge_row, edge_col, edge_val, cnt, ep);
        spmm_csr_kernel<<<M_SEG * 64 / 256, 256, 0, stream>>>(xb, ep, ofs, tmpb);
        dim3 grid(M_PAD / 128, D_FEAT / 128);
        gemm_mfma_kernel<<<grid, 256, 0, stream>>>(tmpb, Wt, bias, out);
    } else {
        float* tmp = (float*)d_ws;
        hipMemsetAsync(tmp, 0, (size_t)N_NODES * D_FEAT * sizeof(float), stream);
        const long long total_threads = (long long)TOT_E * 64;
        spmm_scatter_kernel<<<(int)((total_threads + 255) / 256), 256, 0, stream>>>(
            x, edge_row, edge_col, edge_val, tmp);
        dim3 grid2((N_NODES + 63) / 64, D_FEAT / 64);
        gemm_bias_kernel<<<grid2, 256, 0, stream>>>(tmp, weight, bias, out);
    }
}